// Round 1
// baseline (611.917 us; speedup 1.0000x reference)
//
#include <hip/hip_runtime.h>
#include <math.h>

// ---------------------------------------------------------------------------
// HierarchicalVQEncoder forward.
//
// Key fact: in eval mode assign = hard one-hot (soft terms cancel exactly),
// so out[b,t] depends ONLY on (idx1[b], idx2[b,t]).  8*32 = 256 possible
// output rows -> precompute table, gather.
//
// idx2 derivation (argmax invariant to positive per-token scaling):
//   r      = relu(ln(x @ Wl1^T + bl1))                    (32768,256)
//   v      = r @ Wc^T + bc,  Wc = Wtb@Wl2, bc = Wtb@bl2+btb   (per-token, 64)
//   hb     = ln(v);  logits_k = l2n(hb) . l2n(cb2[i1,k])
//   argmax_k logits_k == argmax_k [ (v - mean(v)) . cbar_k ]
//                     == argmax_k [ r . H[:,k] + f_k ]
//   H[n,k] = sum_c Wc[c,n]*cbar[k,c] - (sum_c Wc[c,n]/64) * sum_c cbar[k,c]
//   f_k    = sum_c bc[c]*cbar[k,c]   - (sum_c bc[c]/64)   * sum_c cbar[k,c]
//
// Precision: idx flips are the only failure mode -> big GEMM in fp32,
// everything cheap in fp64 accumulation.
// ---------------------------------------------------------------------------

#define TM 32
#define KB 32

__device__ __forceinline__ double blk_sum_256(double v, double* red){
  const int tid = threadIdx.x;
  red[tid] = v; __syncthreads();
  #pragma unroll
  for(int s=128; s>0; s>>=1){ if(tid < s) red[tid] += red[tid+s]; __syncthreads(); }
  const double r = red[0]; __syncthreads();
  return r;
}

// ---- P1: partial sums for mean/std over T -------------------------------
__global__ __launch_bounds__(256) void hvq_p1_partial(
    const float* __restrict__ x, double* __restrict__ psum, double* __restrict__ psumsq){
  const int tc = blockIdx.x;          // 0..15, 128 t each
  const int b  = blockIdx.y;          // 0..15
  const int d4 = threadIdx.x * 4;
  const float* xp = x + ((size_t)(b*2048 + tc*128))*1024 + d4;
  double s0=0,s1=0,s2=0,s3=0, q0=0,q1=0,q2=0,q3=0;
  for(int t=0;t<128;t++){
    const float4 v = *(const float4*)&xp[(size_t)t*1024];
    s0 += v.x; q0 += (double)v.x*v.x;
    s1 += v.y; q1 += (double)v.y*v.y;
    s2 += v.z; q2 += (double)v.z*v.z;
    s3 += v.w; q3 += (double)v.w*v.w;
  }
  const size_t o = ((size_t)(b*16+tc))*1024 + d4;
  psum[o+0]=s0; psum[o+1]=s1; psum[o+2]=s2; psum[o+3]=s3;
  psumsq[o+0]=q0; psumsq[o+1]=q1; psumsq[o+2]=q2; psumsq[o+3]=q3;
}

__global__ __launch_bounds__(256) void hvq_p1_final(
    const double* __restrict__ psum, const double* __restrict__ psumsq, float* __restrict__ g_in){
  const int i = blockIdx.x*256 + threadIdx.x;   // b*1024 + d
  const int b = i >> 10, d = i & 1023;
  double s=0, ss=0;
  for(int tc=0;tc<16;tc++){
    const size_t o = ((size_t)(b*16+tc))*1024 + d;
    s += psum[o]; ss += psumsq[o];
  }
  const double mean = s / 2048.0;
  double var = (ss - s*mean) / 2047.0;          // ddof=1
  if(var < 0) var = 0;
  g_in[i] = (float)(mean + sqrt(var));
}

// ---- P2: global encoder -> idx1, normalized codebook cbar ---------------
__global__ __launch_bounds__(256) void hvq_p2(
    const float* __restrict__ g_in,
    const float* __restrict__ Wg1, const float* __restrict__ bg1,
    const float* __restrict__ Wg2, const float* __restrict__ bg2,
    const float* __restrict__ Wp,  const float* __restrict__ bp,
    const float* __restrict__ cb1, const float* __restrict__ cb2,
    int* __restrict__ idx1_g, float* __restrict__ cbn){
  __shared__ float gin[1024];
  __shared__ float sa[256];
  __shared__ float sb[128];
  __shared__ float sh[128];
  __shared__ double red[256];
  __shared__ double lg[8];
  __shared__ double nrm[32];
  __shared__ int i1s;
  const int b = blockIdx.x, tid = threadIdx.x;

  for(int i=tid;i<1024;i+=256) gin[i] = g_in[b*1024+i];
  __syncthreads();

  // z = ln-input: g_in @ Wg1^T + bg1   (fp64 acc)
  double z = 0;
  {
    const float* wr = Wg1 + (size_t)tid*1024;
    for(int d=0; d<1024; d+=4){
      const float4 w = *(const float4*)&wr[d];
      z += (double)gin[d]*w.x + (double)gin[d+1]*w.y
         + (double)gin[d+2]*w.z + (double)gin[d+3]*w.w;
    }
    z += (double)bg1[tid];
  }
  const double mz = blk_sum_256(z, red) / 256.0;
  const double dz = z - mz;
  const double vz = blk_sum_256(dz*dz, red) / 256.0;
  double a = dz / sqrt(vz + 1e-5);
  if(a < 0) a = 0;
  sa[tid] = (float)a;
  __syncthreads();

  if(tid < 128){
    const float* wr = Wg2 + (size_t)tid*256;
    double g = 0;
    for(int i=0;i<256;i++) g += (double)sa[i]*(double)wr[i];
    sb[tid] = (float)(g + (double)bg2[tid]);
  }
  __syncthreads();

  double h = 0;
  if(tid < 128){
    const float* wr = Wp + (size_t)tid*128;
    for(int i=0;i<128;i++) h += (double)sb[i]*(double)wr[i];
    h += (double)bp[tid];
  }
  const double mh = blk_sum_256(tid<128 ? h : 0.0, red) / 128.0;
  const double dh = (tid<128) ? (h - mh) : 0.0;
  const double vh = blk_sum_256(dh*dh, red) / 128.0;
  const double h1 = dh / sqrt(vh + 1e-5);
  if(tid < 128) sh[tid] = (float)h1;
  const double nh2 = blk_sum_256(tid<128 ? h1*h1 : 0.0, red);
  const double normh = sqrt(nh2);
  __syncthreads();

  if(tid < 8){
    const float* cr = cb1 + tid*128;
    double dsum=0, n2=0;
    for(int i=0;i<128;i++){ const double c=(double)cr[i]; dsum += (double)sh[i]*c; n2 += c*c; }
    lg[tid] = dsum / (fmax(normh,1e-12) * fmax(sqrt(n2),1e-12));
  }
  __syncthreads();
  if(tid == 0){
    int bi=0; double bv=lg[0];
    for(int j=1;j<8;j++) if(lg[j] > bv){ bv=lg[j]; bi=j; }  // first-max tie-break
    i1s = bi; idx1_g[b] = bi;
  }
  __syncthreads();
  const int i1 = i1s;
  if(tid < 32){
    const float* cr = cb2 + ((size_t)i1*32 + tid)*64;
    double n2=0;
    for(int c=0;c<64;c++){ const double v=(double)cr[c]; n2 += v*v; }
    nrm[tid] = fmax(sqrt(n2), 1e-12);
  }
  __syncthreads();
  for(int i=tid;i<2048;i+=256){
    const int kk = i >> 6, c = i & 63;
    cbn[(size_t)b*2048 + i] = (float)((double)cb2[((size_t)i1*32+kk)*64 + c] / nrm[kk]);
  }
}

// ---- P3a: transpose Wl1 (256,1024) -> Wl1T (1024,256) -------------------
__global__ __launch_bounds__(256) void hvq_p3a(
    const float* __restrict__ Wl1, float* __restrict__ Wl1T){
  const int o = blockIdx.x*1024 + threadIdx.x*4;   // index into Wl1T, 262144 total
  const int k = o >> 8;
  const int n = o & 255;
  float4 v;
  v.x = Wl1[(size_t)(n+0)*1024 + k];
  v.y = Wl1[(size_t)(n+1)*1024 + k];
  v.z = Wl1[(size_t)(n+2)*1024 + k];
  v.w = Wl1[(size_t)(n+3)*1024 + k];
  *(float4*)&Wl1T[o] = v;
}

// ---- P3b: Wc = Wtb@Wl2 (64,256), bc = Wtb@bl2 + btb (fp64) --------------
__global__ __launch_bounds__(256) void hvq_p3b(
    const float* __restrict__ Wtb, const float* __restrict__ Wl2,
    const float* __restrict__ bl2, const float* __restrict__ btb,
    double* __restrict__ Wc_d, double* __restrict__ bc_d){
  const int c = blockIdx.x, n = threadIdx.x;
  double acc = 0;
  for(int j=0;j<256;j++) acc += (double)Wtb[c*256+j] * (double)Wl2[j*256+n];
  Wc_d[c*256+n] = acc;
  if(n == 0){
    double a = 0;
    for(int j=0;j<256;j++) a += (double)Wtb[c*256+j] * (double)bl2[j];
    bc_d[c] = a + (double)btb[c];
  }
}

// ---- P3c: folded score matrices H[b][n][k], f[b][k] ---------------------
__global__ __launch_bounds__(256) void hvq_p3c(
    const double* __restrict__ Wc_d, const double* __restrict__ bc_d,
    const float* __restrict__ cbn, float* __restrict__ H, float* __restrict__ f){
  const int ng = blockIdx.x;   // 0..7
  const int b  = blockIdx.y;   // 0..15
  const int n  = ng*32 + (threadIdx.x & 31);
  const int kq = threadIdx.x >> 5;   // 0..7
  double su = 0;
  for(int c=0;c<64;c++) su += Wc_d[c*256+n];
  su /= 64.0;
  for(int t=0;t<4;t++){
    const int k = kq*4 + t;
    const float* cb = cbn + ((size_t)b*32 + k)*64;
    double acc=0, sk=0;
    for(int c=0;c<64;c++){ const double cc=(double)cb[c]; acc += Wc_d[c*256+n]*cc; sk += cc; }
    H[((size_t)b*256 + n)*32 + k] = (float)(acc - su*sk);
  }
  if(ng == 0 && threadIdx.x < 32){
    const int k = threadIdx.x;
    const float* cb = cbn + ((size_t)b*32 + k)*64;
    double acc=0, sk=0, sbc=0;
    for(int c=0;c<64;c++){ const double cc=(double)cb[c]; acc += bc_d[c]*cc; sk += cc; sbc += bc_d[c]; }
    f[b*32 + k] = (float)(acc - (sbc/64.0)*sk);
  }
}

// ---- P4: output table (8*32 rows x 256) ---------------------------------
__global__ __launch_bounds__(256) void hvq_p4(
    const float* __restrict__ cb2, const float* __restrict__ cb1,
    const float* __restrict__ Wfb, const float* __restrict__ bfb,
    const float* __restrict__ Wf,  const float* __restrict__ bf,
    float* __restrict__ table){
  const int i1 = blockIdx.x >> 5, k2 = blockIdx.x & 31;
  __shared__ float e[64];
  __shared__ float fused[384];
  __shared__ double red[256];
  const int j = threadIdx.x;
  if(j < 64) e[j] = cb2[((size_t)i1*32 + k2)*64 + j];
  if(j >= 128) fused[256 + (j-128)] = cb1[i1*128 + (j-128)];
  __syncthreads();

  double t = 0;
  {
    const float* wr = Wfb + (size_t)j*64;
    for(int c=0;c<64;c++) t += (double)e[c]*(double)wr[c];
    t += (double)bfb[j];
  }
  double m = blk_sum_256(t, red) / 256.0;
  double d = t - m;
  double v = blk_sum_256(d*d, red) / 256.0;
  fused[j] = (float)(d / sqrt(v + 1e-5));
  __syncthreads();

  double o = 0;
  {
    const float* wr = Wf + (size_t)j*384;
    for(int i=0;i<384;i++) o += (double)fused[i]*(double)wr[i];
    o += (double)bf[j];
  }
  m = blk_sum_256(o, red) / 256.0;
  d = o - m;
  v = blk_sum_256(d*d, red) / 256.0;
  double r = d / sqrt(v + 1e-5);
  if(r < 0) r = 0;
  table[(size_t)blockIdx.x*256 + j] = (float)r;
}

// ---- Main: fused GEMM (x@Wl1^T) + LN + ReLU + scores + argmax + gather --
__global__ __launch_bounds__(256) void hvq_main(
    const float* __restrict__ x, const float* __restrict__ Wl1T,
    const float* __restrict__ bl1, const float* __restrict__ H,
    const float* __restrict__ f, const int* __restrict__ idx1,
    const float* __restrict__ table, float* __restrict__ out){
  __shared__ float wsT[KB*256];   // [kk][n] 32KB; aliased as rT[256][32] after K-loop
  __shared__ float xs[TM*KB];     // [m][kk] 4KB
  __shared__ int kstar[TM];

  const int tid = threadIdx.x;
  const int tx = tid & 31, ty = tid >> 5;
  const int b  = blockIdx.y;
  const int t0 = blockIdx.x * TM;
  const float* xbase = x + ((size_t)(b*2048 + t0))*1024;

  float acc[4][8];
  #pragma unroll
  for(int j=0;j<4;j++)
    #pragma unroll
    for(int c=0;c<8;c++) acc[j][c] = 0.f;

  float bn[8];
  #pragma unroll
  for(int c=0;c<4;c++){ bn[c] = bl1[tx*4+c]; bn[c+4] = bl1[128 + tx*4 + c]; }

  const int sm = tid >> 3;         // xs staging row (0..31)
  const int scol = (tid & 7)*4;    // xs staging col

  for(int kt=0; kt<1024/KB; kt++){
    const int k0 = kt*KB;
    // W tile: contiguous 32KB block of Wl1T, layout lands as [kk][n]
    const float* wsrc = Wl1T + (size_t)k0*256;
    #pragma unroll
    for(int i=0;i<8;i++){
      const int off = i*1024 + tid*4;
      *(float4*)&wsT[off] = *(const float4*)&wsrc[off];
    }
    // x tile
    *(float4*)&xs[sm*KB + scol] = *(const float4*)&xbase[(size_t)sm*1024 + k0 + scol];
    __syncthreads();

    #pragma unroll 8
    for(int kk=0;kk<KB;kk++){
      const float4 w0 = *(const float4*)&wsT[kk*256 + tx*4];
      const float4 w1 = *(const float4*)&wsT[kk*256 + 128 + tx*4];
      #pragma unroll
      for(int j=0;j<4;j++){
        const float xv = xs[(ty*4+j)*KB + kk];
        acc[j][0] = fmaf(xv, w0.x, acc[j][0]);
        acc[j][1] = fmaf(xv, w0.y, acc[j][1]);
        acc[j][2] = fmaf(xv, w0.z, acc[j][2]);
        acc[j][3] = fmaf(xv, w0.w, acc[j][3]);
        acc[j][4] = fmaf(xv, w1.x, acc[j][4]);
        acc[j][5] = fmaf(xv, w1.y, acc[j][5]);
        acc[j][6] = fmaf(xv, w1.z, acc[j][6]);
        acc[j][7] = fmaf(xv, w1.w, acc[j][7]);
      }
    }
    __syncthreads();
  }

  // bias + LN(256) over row (reduce across the 32 tx lanes) + ReLU -> rT
  float* rT = wsT;    // [n][m] = [256][32]
  #pragma unroll
  for(int j=0;j<4;j++){
    float s = 0.f;
    #pragma unroll
    for(int c=0;c<8;c++){ acc[j][c] += bn[c]; s += acc[j][c]; }
    #pragma unroll
    for(int off=16;off>=1;off>>=1) s += __shfl_xor(s, off);
    const float mean = s * (1.f/256.f);
    float d2 = 0.f;
    #pragma unroll
    for(int c=0;c<8;c++){ const float dv = acc[j][c]-mean; d2 += dv*dv; }
    #pragma unroll
    for(int off=16;off>=1;off>>=1) d2 += __shfl_xor(d2, off);
    const float inv = 1.f / sqrtf(d2*(1.f/256.f) + 1e-5f);
    const int m = ty*4 + j;
    #pragma unroll
    for(int c=0;c<8;c++){
      float r = (acc[j][c]-mean)*inv;
      r = fmaxf(r, 0.f);
      const int n = (c < 4) ? (tx*4 + c) : (128 + tx*4 + (c-4));
      rT[n*TM + m] = r;
    }
  }
  __syncthreads();

  // scores[m][k] = f_k + sum_n r[m][n]*H[b][n][k];  argmax over k (32 lanes)
  const int k = tid & 31, mg = tid >> 5;
  const float* Hb = H + (size_t)b*256*32 + k;
  const float fk = f[b*32 + k];
  float s0=fk, s1=fk, s2=fk, s3=fk;
  #pragma unroll 4
  for(int n=0;n<256;n++){
    const float4 rm = *(const float4*)&rT[n*TM + mg*4];
    const float hv = Hb[(size_t)n*32];
    s0 = fmaf(rm.x, hv, s0);
    s1 = fmaf(rm.y, hv, s1);
    s2 = fmaf(rm.z, hv, s2);
    s3 = fmaf(rm.w, hv, s3);
  }
  float scv[4] = {s0, s1, s2, s3};
  #pragma unroll
  for(int j=0;j<4;j++){
    float best = scv[j]; int bi = k;
    #pragma unroll
    for(int off=16;off>=1;off>>=1){
      const float ov = __shfl_xor(best, off);
      const int   oi = __shfl_xor(bi, off);
      if(ov > best || (ov == best && oi < bi)){ best = ov; bi = oi; }
    }
    if(k == 0) kstar[mg*4 + j] = bi;
  }
  __syncthreads();

  // gather output rows from table
  const int i1 = idx1[b];
  float* ob = out + ((size_t)(b*2048 + t0))*256;
  for(int m=0;m<TM;m++){
    const float v = table[((size_t)(i1*32 + kstar[m]))*256 + tid];
    ob[(size_t)m*256 + tid] = v;
  }
}

// ---------------------------------------------------------------------------
extern "C" void kernel_launch(void* const* d_in, const int* in_sizes, int n_in,
                              void* d_out, int out_size, void* d_ws, size_t ws_size,
                              hipStream_t stream){
  const float* x   = (const float*)d_in[0];
  const float* Wg1 = (const float*)d_in[1];
  const float* bg1 = (const float*)d_in[2];
  const float* Wg2 = (const float*)d_in[3];
  const float* bg2 = (const float*)d_in[4];
  const float* Wl1 = (const float*)d_in[5];
  const float* bl1 = (const float*)d_in[6];
  const float* Wl2 = (const float*)d_in[7];
  const float* bl2 = (const float*)d_in[8];
  const float* Wp  = (const float*)d_in[9];
  const float* bp  = (const float*)d_in[10];
  const float* cb1 = (const float*)d_in[11];
  const float* Wtb = (const float*)d_in[12];
  const float* btb = (const float*)d_in[13];
  const float* Wfb = (const float*)d_in[14];
  const float* bfb = (const float*)d_in[15];
  const float* cb2 = (const float*)d_in[16];
  const float* Wf  = (const float*)d_in[17];
  const float* bf  = (const float*)d_in[18];
  float* out = (float*)d_out;

  char* w = (char*)d_ws;
  double* psum   = (double*)w; w += (size_t)16*16*1024*8;   // 2 MB
  double* psumsq = (double*)w; w += (size_t)16*16*1024*8;   // 2 MB
  double* Wc_d   = (double*)w; w += (size_t)64*256*8;
  double* bc_d   = (double*)w; w += (size_t)64*8;
  float*  g_in   = (float*)w;  w += (size_t)16*1024*4;
  float*  cbn    = (float*)w;  w += (size_t)16*32*64*4;
  int*    idx1   = (int*)w;    w += 64;
  float*  Wl1T   = (float*)w;  w += (size_t)1024*256*4;     // 1 MB
  float*  Hq     = (float*)w;  w += (size_t)16*256*32*4;    // 512 KB
  float*  fq     = (float*)w;  w += (size_t)16*32*4;
  float*  table  = (float*)w;  w += (size_t)256*256*4;      // 256 KB

  hvq_p1_partial<<<dim3(16,16), 256, 0, stream>>>(x, psum, psumsq);
  hvq_p3a<<<256, 256, 0, stream>>>(Wl1, Wl1T);
  hvq_p3b<<<64, 256, 0, stream>>>(Wtb, Wl2, bl2, btb, Wc_d, bc_d);
  hvq_p4<<<256, 256, 0, stream>>>(cb2, cb1, Wfb, bfb, Wf, bf, table);
  hvq_p1_final<<<64, 256, 0, stream>>>(psum, psumsq, g_in);
  hvq_p2<<<16, 256, 0, stream>>>(g_in, Wg1, bg1, Wg2, bg2, Wp, bp, cb1, cb2, idx1, cbn);
  hvq_p3c<<<dim3(8,16), 256, 0, stream>>>(Wc_d, bc_d, cbn, Hq, fq);
  hvq_main<<<dim3(64,16), 256, 0, stream>>>(x, Wl1T, bl1, Hq, fq, idx1, table, out);
}